// Round 6
// baseline (481.005 us; speedup 1.0000x reference)
//
#include <hip/hip_runtime.h>

// ErosionLayer: B=16, W=512, ITERS=10, fp32. PASSING numeric recipe (r5..r13,
// absmax 0.02734375): XLA-style greedy FMA via explicit fmaf() at exact sites,
// contract(off) elsewhere, correctly-rounded fp32 div/sqrt. cell_math op order
// is the frozen recipe -- only PROVABLY bit-exact simplifications allowed.
//
// r17 PASSED 353.6us: ping-pong dbuf of s/w/v across dispatches kills the
// inter-block race. r18 PASSED 322.6us: bit-exact DCE + HH=8 (ratio 1.25);
// 56 KiB LDS -> 2 blocks/CU, Occ 32%, busy 77% (latency-limited).
// r19 REGRESSED 404us: LDS aliasing (32 KiB) worked, but PAIRED phase-1 rows
// + forced VGPR cap 64 -> allocator spilled (VGPR_Count 32, FETCH +49 MB,
// WRITE +92 MB = scratch round-trips), busy 58%.
//
// r20 (this round): aliasing with SINGLE-ROW retire -- same live set as r18
// (52 VGPR at cap 128), so cap 64 should hold without spill.
// Hazard proof: slot i is read only by rows j<=i (row j reads slots j..j+4);
// schedule {compute row i -> barrier -> write slot i} is race-free with one
// barrier per row; writes to slot i overlap compute of row i+1 (reads slots
// i+1..i+5, disjoint); new content first read in phase 2 after final barrier.
// Geometry: A = 16 rows [r0-4, r0+11], terrain-k retires into slots 0..11
// (slot i = row r0-2+i); LDS 32 KiB -> 4 blocks/CU (wave-capped, 32 waves =
// 100%); grid 1024 = exactly one residency round; 13 barriers/dispatch
// amortized across 4 independent blocks/CU. Phase-2 rowOfs r0-2; stale slots
// 12..15 (and 0..1 at r0=0) provably unread via clamps (verified r0 0/504).
// Inter-dispatch s/w/v dbuf unchanged. Bit-exact vs r18.
// FINAL skips dead s/w/v stores.
#pragma clang fp contract(off)

constexpr int WW   = 512;
constexpr int NPIX = WW * WW;      // 2^18
constexpr int NTOT = 16 * NPIX;    // 4194304
constexpr int HH   = 8;            // owned rows per block
constexpr int AR   = 16;           // LDS rows [r0-4, r0+11]; terrain-k aliased
constexpr int BR   = 12;           // phase-1 computed rows [r0-2, r0+9]
constexpr int NBLK = 16 * (WW / HH);   // 1024

// FROZEN r5/r6 math (+ r18 provably-bit-exact factor/rY/den removal);
// all terrain reads from an LDS tile with row offset.
__device__ __forceinline__ void cell_math(
    const float* __restrict__ lds, int rowOfs, int r, int c,
    float rain_v, float gno_v,
    float rr, float evapr, float minhd, float heps, float gravr, float sccr,
    float diss, float depo,
    float& s_io, float& w_io, float& v_io, float& t_out, bool fin)
{
    #pragma clang fp contract(off)
    const float CELLW = 0.390625f;            // 200/512, exact

    float t_c = lds[(r - rowOfs) * WW + c];

    float w = fmaf(rr, rain_v, w_io);

    float dx, dy;
    if      (r == 0)      dx = 0.5f * fmaf(t_c, 1.1f, -t_c);
    else if (r == WW - 1) dx = 0.5f * fmaf(t_c, 0.9f, -t_c);
    else dx = 0.5f * (lds[(r + 1 - rowOfs) * WW + c] - lds[(r - 1 - rowOfs) * WW + c]);
    if      (c == 0)      dy = 0.5f * fmaf(t_c, 1.1f, -t_c);
    else if (c == WW - 1) dy = 0.5f * fmaf(t_c, 0.9f, -t_c);
    else dy = 0.5f * (lds[(r - rowOfs) * WW + c + 1] - lds[(r - rowOfs) * WW + c - 1]);

    float mag = sqrtf(fmaf(dx, dx, dy * dy) + 1e-11f);
    // r18 bit-exact DCE: mag >= sqrt(1e-11) = 3.16e-6 > 1e-10, so
    // factor = relu(1e-10 - mag) == 0, rY unused, den = mag + 0 = mag.
    // fmaf(0, rX, dx) == dx (sign-of-zero flip absorbed downstream).
    float fdx = dx / mag;                     // |fdx| <= 1 + ~3ulp
    float fdy = dy / mag;                     // |fdy| <= 1 + ~3ulp

    float fx  = (float)c + (-fdx);
    float fy  = (float)r + (-fdy);
    float x0f = floorf(fx), y0f = floorf(fy);
    float wx1 = fx - x0f;
    float wy1 = fy - y0f;
    int x0 = (int)x0f, y0 = (int)y0f;
    int x1 = x0 + 1,   y1 = y0 + 1;

    bool vx0 = (x0 >= 0) & (x0 < WW);
    bool vx1 = (x1 >= 0) & (x1 < WW);
    bool vy0 = (y0 >= 0) & (y0 < WW);
    bool vy1 = (y1 >= 0) & (y1 < WW);
    int x0c = min(max(x0, 0), WW - 1), x1c = min(max(x1, 0), WW - 1);
    int y0c = min(max(y0, 0), WW - 1), y1c = min(max(y1, 0), WW - 1);
    int ty0 = y0c - rowOfs, ty1 = y1c - rowOfs;   // in [r-2,r+2]-rowOfs

    float g00 = (vx0 && vy0) ? (lds[ty0 * WW + x0c] - 1.0f) : 0.0f;
    float g10 = (vx1 && vy0) ? (lds[ty0 * WW + x1c] - 1.0f) : 0.0f;
    float g01 = (vx0 && vy1) ? (lds[ty1 * WW + x0c] - 1.0f) : 0.0f;
    float g11 = (vx1 && vy1) ? (lds[ty1 * WW + x1c] - 1.0f) : 0.0f;

    float wx0 = 1.0f - wx1;
    float wy0 = 1.0f - wy1;
    float rowA = fmaf(wx0, g00, wx1 * g10);
    float rowB = fmaf(wx0, g01, wx1 * g11);
    float bil  = fmaf(wy0, rowA, wy1 * rowB);
    float neighbor = bil + 1.0f;

    float hd = t_c - neighbor;

    float v = v_io;
    float s = s_io;

    float hds  = ((hd - heps) > 0.0f) ? 1.0f : 0.0f;  // sign(relu(hd-eps))
    float nhd  = hds * fmaxf(hd, minhd);
    float q1 = nhd / CELLW;
    float q2 = q1 * v;
    float q3 = q2 * w;
    float sdiff = fmaf(-q3, sccr, s);                 // s - sed_cap
    float ftb   = (hd < 0.0f) ? 1.0f : 0.0f;          // relu(sign(-hd))
    float first = fminf(fmaxf(-hd, 0.0f), s);
    float ra = fmaxf(sdiff * depo, 0.0f);
    float rb = fmaxf((-sdiff) * diss, 0.0f);
    float deparg = fmaf(1.0f - ftb, ra - rb, first);
    float dep    = fmaxf(-fmaxf(hd, 0.0f), deparg);

    float s_new = s - dep;
    float t_new = t_c + dep;

    float rn = fmaxf(-fdy, 0.0f);
    float rm = fmaxf(1.0f - fabsf(fdy), 0.0f);
    float rp = fmaxf(fdy, 0.0f);

    float s1 = (c == WW - 1) ? 0.0f : rn * s_new;
    float s3 = (c == 0)      ? 0.0f : rp * s_new;
    s_io = fmaf(rm, s_new, s1) + s3;

    float w1 = (c == WW - 1) ? 0.0f : rn * w;
    float w3 = (c == 0)      ? 0.0f : rp * w;
    float wd = fmaf(rm, w, w1) + w3;
    w_io = wd * (1.0f - evapr);

    v_io = (gravr * hd) / CELLW;

    if (fin) {
        float aa = fmaf(-t_new, 2.0f, 1.0f);          // 1 - t*2 -> fnma
        float bq = 1.0f + aa;
        t_out = fmaxf(bq, 0.0f) - 1.0f;
    } else {
        t_out = t_new;
    }
}

template <bool FIRST, bool FINAL>
__global__ __launch_bounds__(512, 8) void erosion_fused(
    const float* __restrict__ tin, float* __restrict__ tout,
    const float* __restrict__ sed_in, const float* __restrict__ wat_in,
    const float* __restrict__ vel_in,
    float* __restrict__ sed_out, float* __restrict__ wat_out,
    float* __restrict__ vel_out,
    const float* __restrict__ rain0, const float* __restrict__ gno0,
    const float* __restrict__ rain1, const float* __restrict__ gno1,
    const float* __restrict__ s_rain_rate, const float* __restrict__ s_evap,
    const float* __restrict__ s_minhd, const float* __restrict__ s_heps,
    const float* __restrict__ s_grav, const float* __restrict__ s_scc,
    const float* __restrict__ s_diss, const float* __restrict__ s_depo)
{
    #pragma clang fp contract(off)
    __shared__ float A[AR * WW];    // terrain k-1 rows [r0-4, r0+11];
                                    // phase 1 retires slot i -> terrain-k
                                    // row r0-2+i (in-place aliasing)

    const int c   = threadIdx.x;
    const int img = blockIdx.x >> 6;           // 64 tiles per image
    const int r0  = (blockIdx.x & 63) * HH;
    const float* tb = tin + (size_t)img * NPIX;

    float rr    = fmaxf(s_rain_rate[0], 0.0f);
    float evapr = fmaxf(s_evap[0], 0.0f);
    float minhd = s_minhd[0];
    float heps  = s_heps[0];
    float gravr = fmaxf(s_grav[0], 0.0f);
    float sccr  = fmaxf(s_scc[0], 0.0f);
    float diss  = s_diss[0];
    float depo  = s_depo[0];

    // ---- stage terrain k-1 rows [r0-4, r0+11] (float4; transform if FIRST)
    // 4 groups of 128 threads; group rg loads rows {rg, rg+4, rg+8, rg+12};
    // 128 float4 = full 512-col row each. Exact cover of tile rows 0..15.
    {
        const int rg = c >> 7;               // 0..3
        const int c4 = (c & 127) << 2;       // column start (float4 aligned)
        #pragma unroll
        for (int j = 0; j < 4; ++j) {
            int ridx = j * 4 + rg;           // 0..15, each exactly once
            int y = r0 - 4 + ridx;
            if (y >= 0 && y < WW) {
                float4 v = *reinterpret_cast<const float4*>(tb + y * WW + c4);
                if (FIRST) {
                    v.x = (1.0f - v.x) / 2.0f;
                    v.y = (1.0f - v.y) / 2.0f;
                    v.z = (1.0f - v.z) / 2.0f;
                    v.w = (1.0f - v.w) / 2.0f;
                }
                *reinterpret_cast<float4*>(&A[ridx * WW + c4]) = v;
            }
        }
    }
    __syncthreads();

    // ---- phase 1: step k over extended rows [r0-2, r0+9], single-row
    // in-place retire: compute row i (reads slots i..i+4) -> barrier ->
    // write slot i (overlaps compute of row i+1, which reads i+1..i+5).
    // s/w/v read from dbuf set-IN (written only by previous dispatch).
    float sK[HH], wK[HH], vK[HH];
    #pragma unroll
    for (int i = 0; i < BR; ++i) {
        const int x = r0 - 2 + i;
        const bool live = (x >= 0) && (x < WW);   // block-uniform
        float s0 = 0.0f, w0 = 0.0f, v0 = 0.0f, tn = 0.0f;
        if (live) {
            if (!FIRST) {
                int g = img * NPIX + x * WW + c;
                s0 = sed_in[g]; w0 = wat_in[g]; v0 = vel_in[g];
            }
            cell_math(A, r0 - 4, x, c, rain0[x * WW + c], gno0[x * WW + c],
                      rr, evapr, minhd, heps, gravr, sccr, diss, depo,
                      s0, w0, v0, tn, false);
        }
        __syncthreads();   // all reads of slot i complete block-wide
        if (live) {
            A[i * WW + c] = tn;
            if (i >= 2 && i <= HH + 1) {        // owned rows: j = i-2 (const)
                sK[i - 2] = s0; wK[i - 2] = w0; vK[i - 2] = v0;
            }
        }
    }
    __syncthreads();       // terrain-k slots 0..11 visible block-wide

    // ---- phase 2: step k+1 over owned rows [r0, r0+7]; terrain k lives in
    // A slots 0..11 with rowOfs r0-2 (slot j = row r0-2+j). Row x reads
    // slots (x-r0)..(x-r0)+4, subset of 0..11; stale slots 12..15 (and 0..1
    // at r0=0) are clamped away.
    #pragma unroll
    for (int j = 0; j < HH; ++j) {
        int x = r0 + j;
        float s0 = sK[j], w0 = wK[j], v0 = vK[j];
        float tn;
        cell_math(A, r0 - 2, x, c, rain1[x * WW + c], gno1[x * WW + c],
                  rr, evapr, minhd, heps, gravr, sccr, diss, depo,
                  s0, w0, v0, tn, FINAL);
        int g = img * NPIX + x * WW + c;
        tout[g] = tn;
        if (!FINAL) { sed_out[g] = s0; wat_out[g] = w0; vel_out[g] = v0; }
    }
}

extern "C" void kernel_launch(void* const* d_in, const int* in_sizes, int n_in,
                              void* d_out, int out_size, void* d_ws, size_t ws_size,
                              hipStream_t stream) {
    const float* in_terr    = (const float*)d_in[0];
    const float* rain_all   = (const float*)d_in[1];  // (1,10,W,W)
    const float* gnoise_all = (const float*)d_in[2];  // (1,10,W,W)
    const float* p_rr       = (const float*)d_in[3];
    const float* p_evap     = (const float*)d_in[4];
    const float* p_minhd    = (const float*)d_in[5];
    const float* p_heps     = (const float*)d_in[6];
    const float* p_grav     = (const float*)d_in[7];
    const float* p_scc      = (const float*)d_in[8];
    const float* p_diss     = (const float*)d_in[9];
    const float* p_depo     = (const float*)d_in[10];

    float* T0  = (float*)d_out;          // final output
    float* ws  = (float*)d_ws;
    float* T1  = ws;
    float* T2  = ws + (size_t)NTOT;
    float* sA  = ws + (size_t)2 * NTOT;
    float* wA  = ws + (size_t)3 * NTOT;
    float* vA  = ws + (size_t)4 * NTOT;
    float* sB, * wB, * vB;
    if (ws_size >= (size_t)8 * NTOT * sizeof(float)) {
        sB = ws + (size_t)5 * NTOT;
        wB = ws + (size_t)6 * NTOT;
        vB = ws + (size_t)7 * NTOT;
    } else {
        // insufficient workspace: fall back to single-buffer (r14 behavior)
        sB = sA; wB = wA; vB = vA;
    }

    dim3 grid(NBLK), block(512);
    #define RN(k) (rain_all   + (size_t)(k) * NPIX)
    #define GN(k) (gnoise_all + (size_t)(k) * NPIX)
    #define SCAL p_rr, p_evap, p_minhd, p_heps, p_grav, p_scc, p_diss, p_depo

    // steps 0+1: in_terr -> T1; s/w/v: (zeros) -> set A
    erosion_fused<true, false><<<grid, block, 0, stream>>>(
        in_terr, T1, sA, wA, vA, sA, wA, vA, RN(0), GN(0), RN(1), GN(1), SCAL);
    // steps 2+3: T1 -> T2; s/w/v: A -> B
    erosion_fused<false, false><<<grid, block, 0, stream>>>(
        T1, T2, sA, wA, vA, sB, wB, vB, RN(2), GN(2), RN(3), GN(3), SCAL);
    // steps 4+5: T2 -> T1; s/w/v: B -> A
    erosion_fused<false, false><<<grid, block, 0, stream>>>(
        T2, T1, sB, wB, vB, sA, wA, vA, RN(4), GN(4), RN(5), GN(5), SCAL);
    // steps 6+7: T1 -> T2; s/w/v: A -> B
    erosion_fused<false, false><<<grid, block, 0, stream>>>(
        T1, T2, sA, wA, vA, sB, wB, vB, RN(6), GN(6), RN(7), GN(7), SCAL);
    // steps 8+9: T2 -> T0 (= d_out), final transform; s/w/v: B -> (dead)
    erosion_fused<false, true><<<grid, block, 0, stream>>>(
        T2, T0, sB, wB, vB, sA, wA, vA, RN(8), GN(8), RN(9), GN(9), SCAL);

    #undef RN
    #undef GN
    #undef SCAL
}

// Round 7
// 303.593 us; speedup vs baseline: 1.5844x; 1.5844x over previous
//
#include <hip/hip_runtime.h>

// ErosionLayer: B=16, W=512, ITERS=10, fp32. PASSING numeric recipe (r5..r13,
// absmax 0.02734375): XLA-style greedy FMA via explicit fmaf() at exact sites,
// contract(off) elsewhere, correctly-rounded fp32 div/sqrt. cell_math op order
// is the frozen recipe -- only PROVABLY bit-exact simplifications allowed.
//
// History: r17 353.6us (dbuf race fix, HH=4, busy 94-98%). r18 322.6us (DCE +
// HH=8 ratio 1.25; 56 KiB LDS -> Occ 32%, busy 77%). r19/r20 REGRESSED
// (404/481us): forced __launch_bounds__(512,8) VGPR cap 64 < the ~100+ actual
// need of HH=8's 24-float loop-carried state -> massive scratch spill
// (WRITE_SIZE +92..98 MB). Evidence: reported VGPR_Count is ~granule-2
// (actual=2x reported): r18 "52"=104 fits cap 128 no-spill; r19/r20 "32"=64
// at forced cap WITH spill; r17 "24-32"=48-64 under cap 85 no-spill.
//
// r21 (this round): cut LIVE state, not the cap.
//  - Interleave phase 2 into the phase-1 loop: iter i does {phase-1 row
//    x=r0-2+i (reads k-1 slots i..i+4)} -> barrier -> {retire terrain-k into
//    slot i} -> barrier -> {phase-2 row j=i-4 (reads k slots i-4..i)}.
//    sK/wK/vK[j] now live only iters j+2..j+4 (~9 floats in flight vs 24).
//  - Slot-liveness proofs (as r20): slot i's last k-1 reader is phase-1 row i;
//    phase-2 row j reads slots j..j+4 <= i, never racing later writes (slots
//    >= i+1). Clamps keep garbage/stale slots unread at r0=0 (slots 0,1) and
//    r0=504 (slots 10,11) -- re-verified.
//  - __launch_bounds__(512,6): cap 85 actual. If need <=64 -> 8 waves/SIMD,
//    4 blocks/CU (LDS 32 KiB), 32 waves/CU. If 65..85 -> NO SPILL, graceful
//    r18-level fallback. Never forces the r19/r20 spill cliff.
// Geometry: A = 16 rows [r0-4, r0+11]; terrain-k slot m = row r0-2+m; grid
// 1024; recompute ratio 1.25. Inter-dispatch s/w/v ping-pong dbuf unchanged.
// Bit-exact vs r18 (same cell_math, same staged bits per cell).
// FINAL skips dead s/w/v stores.
#pragma clang fp contract(off)

constexpr int WW   = 512;
constexpr int NPIX = WW * WW;      // 2^18
constexpr int NTOT = 16 * NPIX;    // 4194304
constexpr int HH   = 8;            // owned rows per block
constexpr int AR   = 16;           // LDS rows [r0-4, r0+11]; terrain-k aliased
constexpr int BR   = 12;           // phase-1 computed rows [r0-2, r0+9]
constexpr int NBLK = 16 * (WW / HH);   // 1024

// FROZEN r5/r6 math (+ r18 provably-bit-exact factor/rY/den removal);
// all terrain reads from an LDS tile with row offset.
__device__ __forceinline__ void cell_math(
    const float* __restrict__ lds, int rowOfs, int r, int c,
    float rain_v, float gno_v,
    float rr, float evapr, float minhd, float heps, float gravr, float sccr,
    float diss, float depo,
    float& s_io, float& w_io, float& v_io, float& t_out, bool fin)
{
    #pragma clang fp contract(off)
    const float CELLW = 0.390625f;            // 200/512, exact

    float t_c = lds[(r - rowOfs) * WW + c];

    float w = fmaf(rr, rain_v, w_io);

    float dx, dy;
    if      (r == 0)      dx = 0.5f * fmaf(t_c, 1.1f, -t_c);
    else if (r == WW - 1) dx = 0.5f * fmaf(t_c, 0.9f, -t_c);
    else dx = 0.5f * (lds[(r + 1 - rowOfs) * WW + c] - lds[(r - 1 - rowOfs) * WW + c]);
    if      (c == 0)      dy = 0.5f * fmaf(t_c, 1.1f, -t_c);
    else if (c == WW - 1) dy = 0.5f * fmaf(t_c, 0.9f, -t_c);
    else dy = 0.5f * (lds[(r - rowOfs) * WW + c + 1] - lds[(r - rowOfs) * WW + c - 1]);

    float mag = sqrtf(fmaf(dx, dx, dy * dy) + 1e-11f);
    // r18 bit-exact DCE: mag >= sqrt(1e-11) = 3.16e-6 > 1e-10, so
    // factor = relu(1e-10 - mag) == 0, rY unused, den = mag + 0 = mag.
    // fmaf(0, rX, dx) == dx (sign-of-zero flip absorbed downstream).
    float fdx = dx / mag;                     // |fdx| <= 1 + ~3ulp
    float fdy = dy / mag;                     // |fdy| <= 1 + ~3ulp

    float fx  = (float)c + (-fdx);
    float fy  = (float)r + (-fdy);
    float x0f = floorf(fx), y0f = floorf(fy);
    float wx1 = fx - x0f;
    float wy1 = fy - y0f;
    int x0 = (int)x0f, y0 = (int)y0f;
    int x1 = x0 + 1,   y1 = y0 + 1;

    bool vx0 = (x0 >= 0) & (x0 < WW);
    bool vx1 = (x1 >= 0) & (x1 < WW);
    bool vy0 = (y0 >= 0) & (y0 < WW);
    bool vy1 = (y1 >= 0) & (y1 < WW);
    int x0c = min(max(x0, 0), WW - 1), x1c = min(max(x1, 0), WW - 1);
    int y0c = min(max(y0, 0), WW - 1), y1c = min(max(y1, 0), WW - 1);
    int ty0 = y0c - rowOfs, ty1 = y1c - rowOfs;   // in [r-2,r+2]-rowOfs

    float g00 = (vx0 && vy0) ? (lds[ty0 * WW + x0c] - 1.0f) : 0.0f;
    float g10 = (vx1 && vy0) ? (lds[ty0 * WW + x1c] - 1.0f) : 0.0f;
    float g01 = (vx0 && vy1) ? (lds[ty1 * WW + x0c] - 1.0f) : 0.0f;
    float g11 = (vx1 && vy1) ? (lds[ty1 * WW + x1c] - 1.0f) : 0.0f;

    float wx0 = 1.0f - wx1;
    float wy0 = 1.0f - wy1;
    float rowA = fmaf(wx0, g00, wx1 * g10);
    float rowB = fmaf(wx0, g01, wx1 * g11);
    float bil  = fmaf(wy0, rowA, wy1 * rowB);
    float neighbor = bil + 1.0f;

    float hd = t_c - neighbor;

    float v = v_io;
    float s = s_io;

    float hds  = ((hd - heps) > 0.0f) ? 1.0f : 0.0f;  // sign(relu(hd-eps))
    float nhd  = hds * fmaxf(hd, minhd);
    float q1 = nhd / CELLW;
    float q2 = q1 * v;
    float q3 = q2 * w;
    float sdiff = fmaf(-q3, sccr, s);                 // s - sed_cap
    float ftb   = (hd < 0.0f) ? 1.0f : 0.0f;          // relu(sign(-hd))
    float first = fminf(fmaxf(-hd, 0.0f), s);
    float ra = fmaxf(sdiff * depo, 0.0f);
    float rb = fmaxf((-sdiff) * diss, 0.0f);
    float deparg = fmaf(1.0f - ftb, ra - rb, first);
    float dep    = fmaxf(-fmaxf(hd, 0.0f), deparg);

    float s_new = s - dep;
    float t_new = t_c + dep;

    float rn = fmaxf(-fdy, 0.0f);
    float rm = fmaxf(1.0f - fabsf(fdy), 0.0f);
    float rp = fmaxf(fdy, 0.0f);

    float s1 = (c == WW - 1) ? 0.0f : rn * s_new;
    float s3 = (c == 0)      ? 0.0f : rp * s_new;
    s_io = fmaf(rm, s_new, s1) + s3;

    float w1 = (c == WW - 1) ? 0.0f : rn * w;
    float w3 = (c == 0)      ? 0.0f : rp * w;
    float wd = fmaf(rm, w, w1) + w3;
    w_io = wd * (1.0f - evapr);

    v_io = (gravr * hd) / CELLW;

    if (fin) {
        float aa = fmaf(-t_new, 2.0f, 1.0f);          // 1 - t*2 -> fnma
        float bq = 1.0f + aa;
        t_out = fmaxf(bq, 0.0f) - 1.0f;
    } else {
        t_out = t_new;
    }
}

template <bool FIRST, bool FINAL>
__global__ __launch_bounds__(512, 6) void erosion_fused(
    const float* __restrict__ tin, float* __restrict__ tout,
    const float* __restrict__ sed_in, const float* __restrict__ wat_in,
    const float* __restrict__ vel_in,
    float* __restrict__ sed_out, float* __restrict__ wat_out,
    float* __restrict__ vel_out,
    const float* __restrict__ rain0, const float* __restrict__ gno0,
    const float* __restrict__ rain1, const float* __restrict__ gno1,
    const float* __restrict__ s_rain_rate, const float* __restrict__ s_evap,
    const float* __restrict__ s_minhd, const float* __restrict__ s_heps,
    const float* __restrict__ s_grav, const float* __restrict__ s_scc,
    const float* __restrict__ s_diss, const float* __restrict__ s_depo)
{
    #pragma clang fp contract(off)
    __shared__ float A[AR * WW];    // terrain k-1 rows [r0-4, r0+11];
                                    // phase 1 retires slot i -> terrain-k
                                    // row r0-2+i (in-place aliasing)

    const int c   = threadIdx.x;
    const int img = blockIdx.x >> 6;           // 64 tiles per image
    const int r0  = (blockIdx.x & 63) * HH;
    const float* tb = tin + (size_t)img * NPIX;
    const int gbase = img * NPIX + c;

    float rr    = fmaxf(s_rain_rate[0], 0.0f);
    float evapr = fmaxf(s_evap[0], 0.0f);
    float minhd = s_minhd[0];
    float heps  = s_heps[0];
    float gravr = fmaxf(s_grav[0], 0.0f);
    float sccr  = fmaxf(s_scc[0], 0.0f);
    float diss  = s_diss[0];
    float depo  = s_depo[0];

    // ---- stage terrain k-1 rows [r0-4, r0+11] (float4; transform if FIRST)
    // 4 groups of 128 threads; group rg loads rows {rg, rg+4, rg+8, rg+12};
    // 128 float4 = full 512-col row each. Exact cover of tile rows 0..15.
    {
        const int rg = c >> 7;               // 0..3
        const int c4 = (c & 127) << 2;       // column start (float4 aligned)
        #pragma unroll
        for (int j = 0; j < 4; ++j) {
            int ridx = j * 4 + rg;           // 0..15, each exactly once
            int y = r0 - 4 + ridx;
            if (y >= 0 && y < WW) {
                float4 v = *reinterpret_cast<const float4*>(tb + y * WW + c4);
                if (FIRST) {
                    v.x = (1.0f - v.x) / 2.0f;
                    v.y = (1.0f - v.y) / 2.0f;
                    v.z = (1.0f - v.z) / 2.0f;
                    v.w = (1.0f - v.w) / 2.0f;
                }
                *reinterpret_cast<float4*>(&A[ridx * WW + c4]) = v;
            }
        }
    }
    __syncthreads();

    // ---- fused phase 1 + phase 2, single loop, in-place slot retire.
    // Iter i: compute step-k row x=r0-2+i (reads k-1 slots i..i+4) ->
    // barrier -> write slot i (terrain-k row x) -> barrier ->
    // compute step-k+1 owned row j=i-4 (reads k slots i-4..i, all visible).
    // sK/wK/vK[j] live only iters j+2..j+4. All barriers block-uniform.
    float sK[HH], wK[HH], vK[HH];
    #pragma unroll
    for (int i = 0; i < BR; ++i) {
        const int x = r0 - 2 + i;
        const bool live1 = (x >= 0) && (x < WW);   // block-uniform
        float s0 = 0.0f, w0 = 0.0f, v0 = 0.0f, tn = 0.0f;
        if (live1) {
            if (!FIRST) {
                int g = gbase + x * WW;
                s0 = sed_in[g]; w0 = wat_in[g]; v0 = vel_in[g];
            }
            cell_math(A, r0 - 4, x, c, rain0[x * WW + c], gno0[x * WW + c],
                      rr, evapr, minhd, heps, gravr, sccr, diss, depo,
                      s0, w0, v0, tn, false);
        }
        __syncthreads();   // all k-1 reads of slot i complete block-wide
        if (live1) {
            A[i * WW + c] = tn;
            if (i >= 2 && i <= HH + 1) {        // owned rows: j = i-2 (const)
                sK[i - 2] = s0; wK[i - 2] = w0; vK[i - 2] = v0;
            }
        }
        __syncthreads();   // slot i (terrain-k) visible block-wide
        if (i >= 4) {
            const int j  = i - 4;               // 0..7, owned row
            const int x2 = r0 + j;              // always in [0, WW)
            float s2 = sK[j], w2 = wK[j], v2 = vK[j];
            float tn2;
            cell_math(A, r0 - 2, x2, c, rain1[x2 * WW + c], gno1[x2 * WW + c],
                      rr, evapr, minhd, heps, gravr, sccr, diss, depo,
                      s2, w2, v2, tn2, FINAL);
            int g = gbase + x2 * WW;
            tout[g] = tn2;
            if (!FINAL) { sed_out[g] = s2; wat_out[g] = w2; vel_out[g] = v2; }
        }
    }
}

extern "C" void kernel_launch(void* const* d_in, const int* in_sizes, int n_in,
                              void* d_out, int out_size, void* d_ws, size_t ws_size,
                              hipStream_t stream) {
    const float* in_terr    = (const float*)d_in[0];
    const float* rain_all   = (const float*)d_in[1];  // (1,10,W,W)
    const float* gnoise_all = (const float*)d_in[2];  // (1,10,W,W)
    const float* p_rr       = (const float*)d_in[3];
    const float* p_evap     = (const float*)d_in[4];
    const float* p_minhd    = (const float*)d_in[5];
    const float* p_heps     = (const float*)d_in[6];
    const float* p_grav     = (const float*)d_in[7];
    const float* p_scc      = (const float*)d_in[8];
    const float* p_diss     = (const float*)d_in[9];
    const float* p_depo     = (const float*)d_in[10];

    float* T0  = (float*)d_out;          // final output
    float* ws  = (float*)d_ws;
    float* T1  = ws;
    float* T2  = ws + (size_t)NTOT;
    float* sA  = ws + (size_t)2 * NTOT;
    float* wA  = ws + (size_t)3 * NTOT;
    float* vA  = ws + (size_t)4 * NTOT;
    float* sB, * wB, * vB;
    if (ws_size >= (size_t)8 * NTOT * sizeof(float)) {
        sB = ws + (size_t)5 * NTOT;
        wB = ws + (size_t)6 * NTOT;
        vB = ws + (size_t)7 * NTOT;
    } else {
        // insufficient workspace: fall back to single-buffer (r14 behavior)
        sB = sA; wB = wA; vB = vA;
    }

    dim3 grid(NBLK), block(512);
    #define RN(k) (rain_all   + (size_t)(k) * NPIX)
    #define GN(k) (gnoise_all + (size_t)(k) * NPIX)
    #define SCAL p_rr, p_evap, p_minhd, p_heps, p_grav, p_scc, p_diss, p_depo

    // steps 0+1: in_terr -> T1; s/w/v: (zeros) -> set A
    erosion_fused<true, false><<<grid, block, 0, stream>>>(
        in_terr, T1, sA, wA, vA, sA, wA, vA, RN(0), GN(0), RN(1), GN(1), SCAL);
    // steps 2+3: T1 -> T2; s/w/v: A -> B
    erosion_fused<false, false><<<grid, block, 0, stream>>>(
        T1, T2, sA, wA, vA, sB, wB, vB, RN(2), GN(2), RN(3), GN(3), SCAL);
    // steps 4+5: T2 -> T1; s/w/v: B -> A
    erosion_fused<false, false><<<grid, block, 0, stream>>>(
        T2, T1, sB, wB, vB, sA, wA, vA, RN(4), GN(4), RN(5), GN(5), SCAL);
    // steps 6+7: T1 -> T2; s/w/v: A -> B
    erosion_fused<false, false><<<grid, block, 0, stream>>>(
        T1, T2, sA, wA, vA, sB, wB, vB, RN(6), GN(6), RN(7), GN(7), SCAL);
    // steps 8+9: T2 -> T0 (= d_out), final transform; s/w/v: B -> (dead)
    erosion_fused<false, true><<<grid, block, 0, stream>>>(
        T2, T0, sB, wB, vB, sA, wA, vA, RN(8), GN(8), RN(9), GN(9), SCAL);

    #undef RN
    #undef GN
    #undef SCAL
}

// Round 8
// 301.766 us; speedup vs baseline: 1.5940x; 1.0061x over previous
//
#include <hip/hip_runtime.h>
#include <hip/hip_cooperative_groups.h>

namespace cg = cooperative_groups;

// ErosionLayer: B=16, W=512, ITERS=10, fp32. PASSING numeric recipe (r5..r13,
// absmax 0.02734375): XLA-style greedy FMA via explicit fmaf() at exact sites,
// contract(off) elsewhere, correctly-rounded fp32 div/sqrt. cell_math op order
// is the frozen recipe -- only PROVABLY bit-exact simplifications allowed.
//
// History: r17 353.6us (s/w/v ping-pong dbuf kills inter-block race; HH=4).
// r18 322.6us (bit-exact DCE + HH=8 ratio 1.25). r19/r20 REGRESSED: forced
// VGPR cap 64 < live state -> scratch spill (WRITE +92..98 MB). r21 303.6us:
// interleaved phase-2 (j=i-4) cut live state; no spill (WRITE=65536 exactly);
// VALUBusy 81-83%, 50.3us/dispatch. NEW signal: sum(dispatches) ~251us vs
// 303.6 total -> ~52us (17%) lost at dispatch boundaries.
//
// r22 (this round):
//  (1) ONE cooperative launch, 5 step-groups, grid.sync() between groups
//      (removes 4 dispatch boundaries ~40-50us for ~4 syncs ~3-5us each).
//      Co-residency: 1024 blocks = 4/CU (LDS 128<=160 KiB, VGPR ~56<=64 ->
//      8 waves/SIMD). Host queries hipOccupancyMaxActiveBlocksPerMultiprocessor;
//      if <4 -> falls back to the proven r21-style 5-dispatch path (never a
//      forced-cap spill, never a deadlock). s/w/v dbuf still guards the
//      intra-group neighbor race; grid.sync device-scope fences handle
//      cross-XCD visibility of terrain/s/w/v between groups.
//  (2) ONE barrier per loop iter (25 -> 14 per group): phase-2 deferred to
//      j=i-5, reading terrain-k slots i-5..i-1 only -- never slot i written
//      this epoch. Hazards: slot i's last k-1 reader is ph1 row i (pre-
//      barrier); slot i-1 write -> ph2 read separated by iter-i barrier;
//      concurrent iter-i+1 ph1 reads slots i+1..i+5 (disjoint from slot-i
//      write). Epilogue does j=7 after a final barrier. sK live-window grows
//      1 entry (~3 VGPR) -- headroom exists.
// Bit-exact vs r21 (same cell_math, same staged bits; scheduling only).
// FINAL skips dead s/w/v stores.
#pragma clang fp contract(off)

constexpr int WW   = 512;
constexpr int NPIX = WW * WW;      // 2^18
constexpr int NTOT = 16 * NPIX;    // 4194304
constexpr int HH   = 8;            // owned rows per block
constexpr int AR   = 16;           // LDS rows [r0-4, r0+11]; terrain-k aliased
constexpr int BR   = 12;           // phase-1 computed rows [r0-2, r0+9]
constexpr int NBLK = 16 * (WW / HH);   // 1024

// FROZEN r5/r6 math (+ r18 provably-bit-exact factor/rY/den removal);
// all terrain reads from an LDS tile with row offset.
__device__ __forceinline__ void cell_math(
    const float* __restrict__ lds, int rowOfs, int r, int c,
    float rain_v, float gno_v,
    float rr, float evapr, float minhd, float heps, float gravr, float sccr,
    float diss, float depo,
    float& s_io, float& w_io, float& v_io, float& t_out, bool fin)
{
    #pragma clang fp contract(off)
    const float CELLW = 0.390625f;            // 200/512, exact

    float t_c = lds[(r - rowOfs) * WW + c];

    float w = fmaf(rr, rain_v, w_io);

    float dx, dy;
    if      (r == 0)      dx = 0.5f * fmaf(t_c, 1.1f, -t_c);
    else if (r == WW - 1) dx = 0.5f * fmaf(t_c, 0.9f, -t_c);
    else dx = 0.5f * (lds[(r + 1 - rowOfs) * WW + c] - lds[(r - 1 - rowOfs) * WW + c]);
    if      (c == 0)      dy = 0.5f * fmaf(t_c, 1.1f, -t_c);
    else if (c == WW - 1) dy = 0.5f * fmaf(t_c, 0.9f, -t_c);
    else dy = 0.5f * (lds[(r - rowOfs) * WW + c + 1] - lds[(r - rowOfs) * WW + c - 1]);

    float mag = sqrtf(fmaf(dx, dx, dy * dy) + 1e-11f);
    // r18 bit-exact DCE: mag >= sqrt(1e-11) = 3.16e-6 > 1e-10, so
    // factor = relu(1e-10 - mag) == 0, rY unused, den = mag + 0 = mag.
    // fmaf(0, rX, dx) == dx (sign-of-zero flip absorbed downstream).
    float fdx = dx / mag;                     // |fdx| <= 1 + ~3ulp
    float fdy = dy / mag;                     // |fdy| <= 1 + ~3ulp

    float fx  = (float)c + (-fdx);
    float fy  = (float)r + (-fdy);
    float x0f = floorf(fx), y0f = floorf(fy);
    float wx1 = fx - x0f;
    float wy1 = fy - y0f;
    int x0 = (int)x0f, y0 = (int)y0f;
    int x1 = x0 + 1,   y1 = y0 + 1;

    bool vx0 = (x0 >= 0) & (x0 < WW);
    bool vx1 = (x1 >= 0) & (x1 < WW);
    bool vy0 = (y0 >= 0) & (y0 < WW);
    bool vy1 = (y1 >= 0) & (y1 < WW);
    int x0c = min(max(x0, 0), WW - 1), x1c = min(max(x1, 0), WW - 1);
    int y0c = min(max(y0, 0), WW - 1), y1c = min(max(y1, 0), WW - 1);
    int ty0 = y0c - rowOfs, ty1 = y1c - rowOfs;   // in [r-2,r+2]-rowOfs

    float g00 = (vx0 && vy0) ? (lds[ty0 * WW + x0c] - 1.0f) : 0.0f;
    float g10 = (vx1 && vy0) ? (lds[ty0 * WW + x1c] - 1.0f) : 0.0f;
    float g01 = (vx0 && vy1) ? (lds[ty1 * WW + x0c] - 1.0f) : 0.0f;
    float g11 = (vx1 && vy1) ? (lds[ty1 * WW + x1c] - 1.0f) : 0.0f;

    float wx0 = 1.0f - wx1;
    float wy0 = 1.0f - wy1;
    float rowA = fmaf(wx0, g00, wx1 * g10);
    float rowB = fmaf(wx0, g01, wx1 * g11);
    float bil  = fmaf(wy0, rowA, wy1 * rowB);
    float neighbor = bil + 1.0f;

    float hd = t_c - neighbor;

    float v = v_io;
    float s = s_io;

    float hds  = ((hd - heps) > 0.0f) ? 1.0f : 0.0f;  // sign(relu(hd-eps))
    float nhd  = hds * fmaxf(hd, minhd);
    float q1 = nhd / CELLW;
    float q2 = q1 * v;
    float q3 = q2 * w;
    float sdiff = fmaf(-q3, sccr, s);                 // s - sed_cap
    float ftb   = (hd < 0.0f) ? 1.0f : 0.0f;          // relu(sign(-hd))
    float first = fminf(fmaxf(-hd, 0.0f), s);
    float ra = fmaxf(sdiff * depo, 0.0f);
    float rb = fmaxf((-sdiff) * diss, 0.0f);
    float deparg = fmaf(1.0f - ftb, ra - rb, first);
    float dep    = fmaxf(-fmaxf(hd, 0.0f), deparg);

    float s_new = s - dep;
    float t_new = t_c + dep;

    float rn = fmaxf(-fdy, 0.0f);
    float rm = fmaxf(1.0f - fabsf(fdy), 0.0f);
    float rp = fmaxf(fdy, 0.0f);

    float s1 = (c == WW - 1) ? 0.0f : rn * s_new;
    float s3 = (c == 0)      ? 0.0f : rp * s_new;
    s_io = fmaf(rm, s_new, s1) + s3;

    float w1 = (c == WW - 1) ? 0.0f : rn * w;
    float w3 = (c == 0)      ? 0.0f : rp * w;
    float wd = fmaf(rm, w, w1) + w3;
    w_io = wd * (1.0f - evapr);

    v_io = (gravr * hd) / CELLW;

    if (fin) {
        float aa = fmaf(-t_new, 2.0f, 1.0f);          // 1 - t*2 -> fnma
        float bq = 1.0f + aa;
        t_out = fmaxf(bq, 0.0f) - 1.0f;
    } else {
        t_out = t_new;
    }
}

// One 2-step group for one block tile. A = 16 LDS rows [r0-4, r0+11];
// phase 1 retires slot i -> terrain-k row r0-2+i; phase 2 deferred j=i-5.
__device__ __forceinline__ void run_group(
    bool FIRST, bool FINAL,
    const float* __restrict__ tb,          // terrain-in image base
    float* __restrict__ tout,
    const float* __restrict__ sed_in, const float* __restrict__ wat_in,
    const float* __restrict__ vel_in,
    float* __restrict__ sed_out, float* __restrict__ wat_out,
    float* __restrict__ vel_out,
    const float* __restrict__ rain0, const float* __restrict__ gno0,
    const float* __restrict__ rain1, const float* __restrict__ gno1,
    float rr, float evapr, float minhd, float heps, float gravr, float sccr,
    float diss, float depo,
    int img, int r0, int c, float* __restrict__ A)
{
    const int gbase = img * NPIX + c;

    // ---- stage terrain k-1 rows [r0-4, r0+11] (float4; transform if FIRST)
    {
        const int rg = c >> 7;               // 0..3
        const int c4 = (c & 127) << 2;       // column start (float4 aligned)
        #pragma unroll
        for (int j = 0; j < 4; ++j) {
            int ridx = j * 4 + rg;           // 0..15, each exactly once
            int y = r0 - 4 + ridx;
            if (y >= 0 && y < WW) {
                float4 v = *reinterpret_cast<const float4*>(tb + y * WW + c4);
                if (FIRST) {
                    v.x = (1.0f - v.x) / 2.0f;
                    v.y = (1.0f - v.y) / 2.0f;
                    v.z = (1.0f - v.z) / 2.0f;
                    v.w = (1.0f - v.w) / 2.0f;
                }
                *reinterpret_cast<float4*>(&A[ridx * WW + c4]) = v;
            }
        }
    }
    __syncthreads();

    // ---- fused loop, ONE barrier per iter. Iter i:
    //  (a) ph1 row x=r0-2+i (reads k-1 slots i..i+4)
    //  (b) barrier
    //  (c) write slot i (terrain-k) ; ph2 row j=i-5 (reads k slots i-5..i-1)
    // Proofs: slot i last k-1-read at (a) of iter i, write at (c) after (b);
    // ph2's newest read (slot i-1, written iter i-1 (c)) separated by (b) of
    // iter i; concurrent iter i+1 (a) reads slots i+1..i+5, disjoint from
    // the slot-i write. sK[j] written iter j+2, read iter j+5.
    float sK[HH], wK[HH], vK[HH];
    #pragma unroll
    for (int i = 0; i < BR; ++i) {
        const int x = r0 - 2 + i;
        const bool live1 = (x >= 0) && (x < WW);   // block-uniform
        float s0 = 0.0f, w0 = 0.0f, v0 = 0.0f, tn = 0.0f;
        if (live1) {
            if (!FIRST) {
                int g = gbase + x * WW;
                s0 = sed_in[g]; w0 = wat_in[g]; v0 = vel_in[g];
            }
            cell_math(A, r0 - 4, x, c, rain0[x * WW + c], gno0[x * WW + c],
                      rr, evapr, minhd, heps, gravr, sccr, diss, depo,
                      s0, w0, v0, tn, false);
        }
        __syncthreads();   // all k-1 reads of slot i complete block-wide
        if (live1) {
            A[i * WW + c] = tn;
            if (i >= 2 && i <= HH + 1) {        // owned rows: j = i-2 (const)
                sK[i - 2] = s0; wK[i - 2] = w0; vK[i - 2] = v0;
            }
        }
        if (i >= 5) {                           // ph2 row j = i-5 (0..6)
            const int j  = i - 5;
            const int x2 = r0 + j;              // always in [0, WW)
            float s2 = sK[j], w2 = wK[j], v2 = vK[j];
            float tn2;
            cell_math(A, r0 - 2, x2, c, rain1[x2 * WW + c], gno1[x2 * WW + c],
                      rr, evapr, minhd, heps, gravr, sccr, diss, depo,
                      s2, w2, v2, tn2, FINAL);
            int g = gbase + x2 * WW;
            tout[g] = tn2;
            if (!FINAL) { sed_out[g] = s2; wat_out[g] = w2; vel_out[g] = v2; }
        }
    }
    __syncthreads();       // slot 11 (written iter 11) visible block-wide

    // ---- epilogue: ph2 row j = 7 (reads k slots 7..11; at r0=504 clamps
    // keep unwritten slots 10,11 unread: y1c<=511 -> slot<=9)
    {
        const int j  = HH - 1;
        const int x2 = r0 + j;
        float s2 = sK[j], w2 = wK[j], v2 = vK[j];
        float tn2;
        cell_math(A, r0 - 2, x2, c, rain1[x2 * WW + c], gno1[x2 * WW + c],
                  rr, evapr, minhd, heps, gravr, sccr, diss, depo,
                  s2, w2, v2, tn2, FINAL);
        int g = gbase + x2 * WW;
        tout[g] = tn2;
        if (!FINAL) { sed_out[g] = s2; wat_out[g] = w2; vel_out[g] = v2; }
    }
}

// ---- fallback kernel: one 2-step group per dispatch (r21-equivalent) ----
template <bool FIRST, bool FINAL>
__global__ __launch_bounds__(512, 6) void erosion_step(
    const float* __restrict__ tin, float* __restrict__ tout,
    const float* __restrict__ sed_in, const float* __restrict__ wat_in,
    const float* __restrict__ vel_in,
    float* __restrict__ sed_out, float* __restrict__ wat_out,
    float* __restrict__ vel_out,
    const float* __restrict__ rain0, const float* __restrict__ gno0,
    const float* __restrict__ rain1, const float* __restrict__ gno1,
    const float* __restrict__ s_rain_rate, const float* __restrict__ s_evap,
    const float* __restrict__ s_minhd, const float* __restrict__ s_heps,
    const float* __restrict__ s_grav, const float* __restrict__ s_scc,
    const float* __restrict__ s_diss, const float* __restrict__ s_depo)
{
    #pragma clang fp contract(off)
    __shared__ float A[AR * WW];
    const int c   = threadIdx.x;
    const int img = blockIdx.x >> 6;
    const int r0  = (blockIdx.x & 63) * HH;

    float rr    = fmaxf(s_rain_rate[0], 0.0f);
    float evapr = fmaxf(s_evap[0], 0.0f);
    float minhd = s_minhd[0];
    float heps  = s_heps[0];
    float gravr = fmaxf(s_grav[0], 0.0f);
    float sccr  = fmaxf(s_scc[0], 0.0f);
    float diss  = s_diss[0];
    float depo  = s_depo[0];

    run_group(FIRST, FINAL, tin + (size_t)img * NPIX, tout,
              sed_in, wat_in, vel_in, sed_out, wat_out, vel_out,
              rain0, gno0, rain1, gno1,
              rr, evapr, minhd, heps, gravr, sccr, diss, depo,
              img, r0, c, A);
}

// ---- cooperative kernel: all 5 groups, grid.sync between them ----
__global__ __launch_bounds__(512, 6) void erosion_coop(
    const float* __restrict__ tin0, float* __restrict__ T0,
    float* __restrict__ T1, float* __restrict__ T2,
    float* __restrict__ sA, float* __restrict__ wA, float* __restrict__ vA,
    float* __restrict__ sB, float* __restrict__ wB, float* __restrict__ vB,
    const float* __restrict__ rain_all, const float* __restrict__ gno_all,
    const float* __restrict__ s_rain_rate, const float* __restrict__ s_evap,
    const float* __restrict__ s_minhd, const float* __restrict__ s_heps,
    const float* __restrict__ s_grav, const float* __restrict__ s_scc,
    const float* __restrict__ s_diss, const float* __restrict__ s_depo)
{
    #pragma clang fp contract(off)
    __shared__ float A[AR * WW];
    cg::grid_group grid = cg::this_grid();

    const int c   = threadIdx.x;
    const int img = blockIdx.x >> 6;
    const int r0  = (blockIdx.x & 63) * HH;

    float rr    = fmaxf(s_rain_rate[0], 0.0f);
    float evapr = fmaxf(s_evap[0], 0.0f);
    float minhd = s_minhd[0];
    float heps  = s_heps[0];
    float gravr = fmaxf(s_grav[0], 0.0f);
    float sccr  = fmaxf(s_scc[0], 0.0f);
    float diss  = s_diss[0];
    float depo  = s_depo[0];

    #pragma unroll 1
    for (int g = 0; g < 5; ++g) {
        const bool FIRST = (g == 0), FINAL = (g == 4);
        // terrain ping-pong: in_terr->T1->T2->T1->T2->T0
        const float* tin; float* tout;
        if      (g == 0) { tin = tin0; tout = T1; }
        else if (g == 1) { tin = T1;   tout = T2; }
        else if (g == 2) { tin = T2;   tout = T1; }
        else if (g == 3) { tin = T1;   tout = T2; }
        else             { tin = T2;   tout = T0; }
        // s/w/v dbuf (guards intra-group neighbor race): A,A / A,B / B,A / A,B / B,-
        const bool inB  = (g == 2) || (g == 4);
        const bool outB = (g == 1) || (g == 3);
        const float* sin_ = inB ? sB : sA;
        const float* win_ = inB ? wB : wA;
        const float* vin_ = inB ? vB : vA;
        float* sout_ = outB ? sB : sA;
        float* wout_ = outB ? wB : wA;
        float* vout_ = outB ? vB : vA;
        const float* rain0 = rain_all + (size_t)(2 * g) * NPIX;
        const float* gno0  = gno_all  + (size_t)(2 * g) * NPIX;
        const float* rain1 = rain_all + (size_t)(2 * g + 1) * NPIX;
        const float* gno1  = gno_all  + (size_t)(2 * g + 1) * NPIX;

        run_group(FIRST, FINAL, tin + (size_t)img * NPIX, tout,
                  sin_, win_, vin_, sout_, wout_, vout_,
                  rain0, gno0, rain1, gno1,
                  rr, evapr, minhd, heps, gravr, sccr, diss, depo,
                  img, r0, c, A);

        if (g < 4) grid.sync();   // device-scope fence: cross-XCD visibility
    }
}

extern "C" void kernel_launch(void* const* d_in, const int* in_sizes, int n_in,
                              void* d_out, int out_size, void* d_ws, size_t ws_size,
                              hipStream_t stream) {
    const float* in_terr    = (const float*)d_in[0];
    const float* rain_all   = (const float*)d_in[1];  // (1,10,W,W)
    const float* gnoise_all = (const float*)d_in[2];  // (1,10,W,W)
    const float* p_rr       = (const float*)d_in[3];
    const float* p_evap     = (const float*)d_in[4];
    const float* p_minhd    = (const float*)d_in[5];
    const float* p_heps     = (const float*)d_in[6];
    const float* p_grav     = (const float*)d_in[7];
    const float* p_scc      = (const float*)d_in[8];
    const float* p_diss     = (const float*)d_in[9];
    const float* p_depo     = (const float*)d_in[10];

    float* T0  = (float*)d_out;          // final output
    float* ws  = (float*)d_ws;
    float* T1  = ws;
    float* T2  = ws + (size_t)NTOT;
    float* sA  = ws + (size_t)2 * NTOT;
    float* wA  = ws + (size_t)3 * NTOT;
    float* vA  = ws + (size_t)4 * NTOT;
    const bool haveB = ws_size >= (size_t)8 * NTOT * sizeof(float);
    float* sB = haveB ? ws + (size_t)5 * NTOT : sA;
    float* wB = haveB ? ws + (size_t)6 * NTOT : wA;
    float* vB = haveB ? ws + (size_t)7 * NTOT : vA;

    // ---- cooperative path feasibility (host queries only; capture-safe) ----
    static int s_coop_attr = -1;
    if (s_coop_attr < 0) {
        int dev = 0;
        hipGetDevice(&dev);
        int v = 0;
        hipDeviceGetAttribute(&v, hipDeviceAttributeCooperativeLaunch, dev);
        s_coop_attr = v ? 1 : 0;
    }
    static int s_maxB = -1;
    if (s_maxB < 0) {
        int mb = 0;
        hipError_t e = hipOccupancyMaxActiveBlocksPerMultiprocessor(
            &mb, erosion_coop, 512, 0);
        s_maxB = (e == hipSuccess) ? mb : 0;
    }
    // 1024 blocks need 4 blocks/CU on 256 CUs to co-reside.
    const bool coop_ok = haveB && s_coop_attr == 1 && s_maxB >= 4;

    if (coop_ok) {
        void* args[] = {
            (void*)&in_terr, (void*)&T0, (void*)&T1, (void*)&T2,
            (void*)&sA, (void*)&wA, (void*)&vA,
            (void*)&sB, (void*)&wB, (void*)&vB,
            (void*)&rain_all, (void*)&gnoise_all,
            (void*)&p_rr, (void*)&p_evap, (void*)&p_minhd, (void*)&p_heps,
            (void*)&p_grav, (void*)&p_scc, (void*)&p_diss, (void*)&p_depo,
        };
        hipLaunchCooperativeKernel(erosion_coop, dim3(NBLK), dim3(512),
                                   args, 0, stream);
        return;
    }

    // ---- fallback: proven 5-dispatch path (r21 structure, new 1-barrier loop)
    dim3 grid(NBLK), block(512);
    #define RN(k) (rain_all   + (size_t)(k) * NPIX)
    #define GN(k) (gnoise_all + (size_t)(k) * NPIX)
    #define SCAL p_rr, p_evap, p_minhd, p_heps, p_grav, p_scc, p_diss, p_depo

    erosion_step<true, false><<<grid, block, 0, stream>>>(
        in_terr, T1, sA, wA, vA, sA, wA, vA, RN(0), GN(0), RN(1), GN(1), SCAL);
    erosion_step<false, false><<<grid, block, 0, stream>>>(
        T1, T2, sA, wA, vA, sB, wB, vB, RN(2), GN(2), RN(3), GN(3), SCAL);
    erosion_step<false, false><<<grid, block, 0, stream>>>(
        T2, T1, sB, wB, vB, sA, wA, vA, RN(4), GN(4), RN(5), GN(5), SCAL);
    erosion_step<false, false><<<grid, block, 0, stream>>>(
        T1, T2, sA, wA, vA, sB, wB, vB, RN(6), GN(6), RN(7), GN(7), SCAL);
    erosion_step<false, true><<<grid, block, 0, stream>>>(
        T2, T0, sB, wB, vB, sA, wA, vA, RN(8), GN(8), RN(9), GN(9), SCAL);

    #undef RN
    #undef GN
    #undef SCAL
}